// Round 2
// baseline (911.719 us; speedup 1.0000x reference)
//
#include <hip/hip_runtime.h>

#define N_NODESC 100000
#define N_EDGESC 300000
#define N_GRAPHSC 4000
#define IN_F 16
#define HID 256
#define RCHUNK 32

// ---------------- degree / norm / CSR build ----------------

__global__ __launch_bounds__(256) void k_degrees(const int* __restrict__ src,
                                                 const int* __restrict__ dst,
                                                 int* __restrict__ outd,
                                                 int* __restrict__ ind) {
  int e = blockIdx.x * blockDim.x + threadIdx.x;
  if (e < N_EDGESC) {
    atomicAdd(&outd[src[e]], 1);
    atomicAdd(&ind[dst[e]], 1);
  }
}

__global__ __launch_bounds__(256) void k_norms(const int* __restrict__ outd,
                                               const int* __restrict__ ind,
                                               float* __restrict__ onorm,
                                               float* __restrict__ inorm) {
  int i = blockIdx.x * blockDim.x + threadIdx.x;
  if (i < N_NODESC) {
    onorm[i] = rsqrtf((float)max(outd[i], 1));
    inorm[i] = rsqrtf((float)max(ind[i], 1));
  }
}

// single-block exclusive scan of in-degrees -> CSR offsets
__global__ __launch_bounds__(1024) void k_scan(const int* __restrict__ ind,
                                               int* __restrict__ offs) {
  __shared__ int sh[1024];
  const int n = N_NODESC;
  int t = threadIdx.x;
  int chunk = (n + 1023) >> 10;
  int b = t * chunk;
  int e = min(b + chunk, n);
  int s = 0;
  for (int i = b; i < e; ++i) s += ind[i];
  sh[t] = s;
  __syncthreads();
  // Hillis-Steele inclusive scan over 1024 partials
  for (int o = 1; o < 1024; o <<= 1) {
    int x = (t >= o) ? sh[t - o] : 0;
    __syncthreads();
    sh[t] += x;
    __syncthreads();
  }
  int pre = sh[t] - s;  // exclusive prefix for this thread's chunk
  for (int i = b; i < e; ++i) {
    offs[i] = pre;
    pre += ind[i];
  }
  if (t == 1023) offs[n] = sh[1023];
}

__global__ __launch_bounds__(256) void k_fill(const int* __restrict__ src,
                                              const int* __restrict__ dst,
                                              const int* __restrict__ offs,
                                              int* __restrict__ cursor,
                                              int* __restrict__ csr) {
  int e = blockIdx.x * blockDim.x + threadIdx.x;
  if (e < N_EDGESC) {
    int d = dst[e];
    int p = offs[d] + atomicAdd(&cursor[d], 1);
    csr[p] = src[e];
  }
}

// ---------------- layer 1: 16-d aggregation + 16x256 matmul ----------------

__global__ __launch_bounds__(256) void k_agg16(const float* __restrict__ feats,
                                               const int* __restrict__ offs,
                                               const int* __restrict__ csr,
                                               const float* __restrict__ onorm,
                                               const float* __restrict__ inorm,
                                               float* __restrict__ agg1) {
  int gid = blockIdx.x * blockDim.x + threadIdx.x;
  int node = gid >> 4;
  if (node >= N_NODESC) return;
  int f = gid & 15;
  int b = offs[node], e = offs[node + 1];
  float acc = 0.f;
  for (int k = b; k < e; ++k) {
    int s = csr[k];
    acc = fmaf(feats[s * IN_F + f], onorm[s], acc);
  }
  agg1[(size_t)node * IN_F + f] = acc * inorm[node];
}

__global__ __launch_bounds__(256) void k_mm16(const float* __restrict__ agg1,
                                              const float* __restrict__ W,
                                              const float* __restrict__ bias,
                                              float* __restrict__ out) {
  __shared__ float Ws[IN_F * HID];
  __shared__ float bs[HID];
  int t = threadIdx.x;
  for (int i = t; i < IN_F * HID; i += 256) Ws[i] = W[i];
  bs[t] = bias[t];
  __syncthreads();
  for (int node = blockIdx.x; node < N_NODESC; node += gridDim.x) {
    float a[IN_F];
#pragma unroll
    for (int k = 0; k < IN_F; ++k) a[k] = agg1[(size_t)node * IN_F + k];
    float acc = bs[t];
#pragma unroll
    for (int k = 0; k < IN_F; ++k) acc = fmaf(a[k], Ws[k * HID + t], acc);
    out[(size_t)node * HID + t] = acc;
  }
}

// ---------------- 256-d aggregation: one wave per node ----------------

__global__ __launch_bounds__(256) void k_agg256(const float* __restrict__ h,
                                                const int* __restrict__ offs,
                                                const int* __restrict__ csr,
                                                const float* __restrict__ onorm,
                                                const float* __restrict__ inorm,
                                                float* __restrict__ agg) {
  int wid = (int)((blockIdx.x * (size_t)blockDim.x + threadIdx.x) >> 6);
  int lane = threadIdx.x & 63;
  if (wid >= N_NODESC) return;
  int b = offs[wid], e = offs[wid + 1];
  const float4* hp = (const float4*)h;
  float4 acc = make_float4(0.f, 0.f, 0.f, 0.f);
  for (int k = b; k < e; ++k) {
    int s = csr[k];
    float w = onorm[s];
    float4 v = hp[(size_t)s * 64 + lane];
    acc.x = fmaf(v.x, w, acc.x);
    acc.y = fmaf(v.y, w, acc.y);
    acc.z = fmaf(v.z, w, acc.z);
    acc.w = fmaf(v.w, w, acc.w);
  }
  float wi = inorm[wid];
  float4 r = make_float4(acc.x * wi, acc.y * wi, acc.z * wi, acc.w * wi);
  ((float4*)agg)[(size_t)wid * 64 + lane] = r;
}

// ---------------- fp32 GEMM: C[M x 256] = A[M x 256] @ W[256 x 256] + bias ----------------
// 128x128 tile, 256 threads, 8x8 micro-tile.

#define GBM 128
#define GBK 16
#define GLDST 132  // padded row stride (dwords); 132*4 % 16 == 0 so float4 stays aligned

__global__ __launch_bounds__(256) void k_gemm(const float* __restrict__ A,
                                              const float* __restrict__ W,
                                              const float* __restrict__ bias,
                                              float* __restrict__ C, int M) {
  __shared__ float As[GBK * GLDST];
  __shared__ float Bs[GBK * GLDST];
  int t = threadIdx.x;
  int tx = t & 15, ty = t >> 4;
  int bm = blockIdx.x * GBM;
  int bn = blockIdx.y * 128;

  float acc[8][8];
#pragma unroll
  for (int i = 0; i < 8; ++i)
#pragma unroll
    for (int j = 0; j < 8; ++j) acc[i][j] = 0.f;

  int alm = t >> 2;          // 0..63
  int alk = (t & 3) * 4;     // 0,4,8,12
  int br = t >> 5;           // 0..7
  int bc = (t & 31) * 4;     // 0..124

  for (int k0 = 0; k0 < HID; k0 += GBK) {
#pragma unroll
    for (int hh = 0; hh < 2; ++hh) {
      int row = bm + alm + hh * 64;
      float4 av = make_float4(0.f, 0.f, 0.f, 0.f);
      if (row < M) av = *(const float4*)(A + (size_t)row * HID + k0 + alk);
      int m = alm + hh * 64;
      As[(alk + 0) * GLDST + m] = av.x;
      As[(alk + 1) * GLDST + m] = av.y;
      As[(alk + 2) * GLDST + m] = av.z;
      As[(alk + 3) * GLDST + m] = av.w;
    }
#pragma unroll
    for (int hh = 0; hh < 2; ++hh) {
      int r = br + hh * 8;
      float4 bv = *(const float4*)(W + (size_t)(k0 + r) * HID + bn + bc);
      *(float4*)&Bs[r * GLDST + bc] = bv;
    }
    __syncthreads();
#pragma unroll
    for (int k = 0; k < GBK; ++k) {
      float a[8], b[8];
      *(float4*)&a[0] = *(const float4*)&As[k * GLDST + ty * 8];
      *(float4*)&a[4] = *(const float4*)&As[k * GLDST + ty * 8 + 4];
      *(float4*)&b[0] = *(const float4*)&Bs[k * GLDST + tx * 8];
      *(float4*)&b[4] = *(const float4*)&Bs[k * GLDST + tx * 8 + 4];
#pragma unroll
      for (int i = 0; i < 8; ++i)
#pragma unroll
        for (int j = 0; j < 8; ++j) acc[i][j] = fmaf(a[i], b[j], acc[i][j]);
    }
    __syncthreads();
  }

  float bvals[8];
  *(float4*)&bvals[0] = *(const float4*)(bias + bn + tx * 8);
  *(float4*)&bvals[4] = *(const float4*)(bias + bn + tx * 8 + 4);
#pragma unroll
  for (int i = 0; i < 8; ++i) {
    int row = bm + ty * 8 + i;
    if (row < M) {
      float o[8];
#pragma unroll
      for (int j = 0; j < 8; ++j) o[j] = acc[i][j] + bvals[j];
      *(float4*)(C + (size_t)row * HID + bn + tx * 8) = *(float4*)&o[0];
      *(float4*)(C + (size_t)row * HID + bn + tx * 8 + 4) = *(float4*)&o[4];
    }
  }
}

// ---------------- readout: sigmoid-weighted sum + segment max ----------------

__device__ __forceinline__ unsigned fkey(float f) {
  unsigned u = __float_as_uint(f);
  return (u & 0x80000000u) ? ~u : (u | 0x80000000u);
}

__device__ __forceinline__ void flush_group(int g, int lane, const float4& s,
                                            const uint4& mk, float* __restrict__ out,
                                            unsigned* __restrict__ mkeys) {
  float* hp = out + (size_t)g * 512 + (lane << 2);
  atomicAdd(hp + 0, s.x);
  atomicAdd(hp + 1, s.y);
  atomicAdd(hp + 2, s.z);
  atomicAdd(hp + 3, s.w);
  unsigned* mp = mkeys + ((size_t)g << 8) + (lane << 2);
  atomicMax(mp + 0, mk.x);
  atomicMax(mp + 1, mk.y);
  atomicMax(mp + 2, mk.z);
  atomicMax(mp + 3, mk.w);
}

__global__ __launch_bounds__(256) void k_readout(const float* __restrict__ h,
                                                 const int* __restrict__ gids,
                                                 const float* __restrict__ w_atom,
                                                 const float* __restrict__ b_atom,
                                                 float* __restrict__ out,
                                                 unsigned* __restrict__ mkeys) {
  int wid = (int)((blockIdx.x * (size_t)blockDim.x + threadIdx.x) >> 6);
  int lane = threadIdx.x & 63;
  int n0 = wid * RCHUNK;
  if (n0 >= N_NODESC) return;
  int n1 = min(n0 + RCHUNK, N_NODESC);
  float4 wa = ((const float4*)w_atom)[lane];
  float ba = b_atom[0];
  float4 s = make_float4(0.f, 0.f, 0.f, 0.f);
  uint4 mk = make_uint4(0u, 0u, 0u, 0u);
  int cur = gids[n0];
  for (int i = n0; i < n1; ++i) {
    int g = gids[i];
    if (g != cur) {
      flush_group(cur, lane, s, mk, out, mkeys);
      s = make_float4(0.f, 0.f, 0.f, 0.f);
      mk = make_uint4(0u, 0u, 0u, 0u);
      cur = g;
    }
    float4 v = ((const float4*)h)[(size_t)i * 64 + lane];
    float d = fmaf(v.x, wa.x, fmaf(v.y, wa.y, fmaf(v.z, wa.z, v.w * wa.w)));
#pragma unroll
    for (int o = 32; o > 0; o >>= 1) d += __shfl_xor(d, o, 64);
    float wgt = 1.0f / (1.0f + expf(-(d + ba)));
    s.x = fmaf(v.x, wgt, s.x);
    s.y = fmaf(v.y, wgt, s.y);
    s.z = fmaf(v.z, wgt, s.z);
    s.w = fmaf(v.w, wgt, s.w);
    mk.x = max(mk.x, fkey(v.x));
    mk.y = max(mk.y, fkey(v.y));
    mk.z = max(mk.z, fkey(v.z));
    mk.w = max(mk.w, fkey(v.w));
  }
  flush_group(cur, lane, s, mk, out, mkeys);
}

__global__ __launch_bounds__(256) void k_finalize(const unsigned* __restrict__ mkeys,
                                                  float* __restrict__ out) {
  int i = blockIdx.x * blockDim.x + threadIdx.x;
  if (i >= N_GRAPHSC * HID) return;
  int g = i >> 8, c = i & 255;
  unsigned k = mkeys[i];
  float f = 0.0f;  // empty graph (never touched) -> 0, matching isfinite guard
  if (k != 0u) f = (k & 0x80000000u) ? __uint_as_float(k ^ 0x80000000u) : __uint_as_float(~k);
  out[(size_t)g * 512 + 256 + c] = f;
}

// ---------------- predictor MLP: pred = relu(hg @ P1 + pb1) @ P2 + pb2 ----------------
// 16 graphs per block; 32-row K-chunks keep LDS at ~34KB.

__global__ __launch_bounds__(256) void k_pred(const float* __restrict__ hg,
                                              const float* __restrict__ P1,
                                              const float* __restrict__ pb1,
                                              const float* __restrict__ P2,
                                              const float* __restrict__ pb2,
                                              float* __restrict__ pred) {
  __shared__ float P1s[32 * 256];
  __shared__ float hgt[32 * 16];
  int t = threadIdx.x;
  int g0 = blockIdx.x * 16;
  int tx = t & 63;
  int tg = t >> 6;
  float acc[4][4];
#pragma unroll
  for (int a = 0; a < 4; ++a)
#pragma unroll
    for (int b = 0; b < 4; ++b) acc[a][b] = 0.f;

  for (int kc = 0; kc < 512; kc += 32) {
    const float4* srcp = (const float4*)(P1 + (size_t)kc * 256);
    float4* dstp = (float4*)P1s;
    for (int i = t; i < 2048; i += 256) dstp[i] = srcp[i];
    {
      int g = t & 15, kk = t >> 4;  // kk in 0..15, 2 k-elems each
      const float* hrow = hg + (size_t)(g0 + g) * 512 + kc;
#pragma unroll
      for (int j = 0; j < 2; ++j) hgt[(kk * 2 + j) * 16 + g] = hrow[kk * 2 + j];
    }
    __syncthreads();
#pragma unroll 8
    for (int k = 0; k < 32; ++k) {
      float4 pv = *(const float4*)&P1s[k * 256 + (tx << 2)];
      float4 hv = *(const float4*)&hgt[(k << 4) + (tg << 2)];
      acc[0][0] = fmaf(hv.x, pv.x, acc[0][0]);
      acc[0][1] = fmaf(hv.x, pv.y, acc[0][1]);
      acc[0][2] = fmaf(hv.x, pv.z, acc[0][2]);
      acc[0][3] = fmaf(hv.x, pv.w, acc[0][3]);
      acc[1][0] = fmaf(hv.y, pv.x, acc[1][0]);
      acc[1][1] = fmaf(hv.y, pv.y, acc[1][1]);
      acc[1][2] = fmaf(hv.y, pv.z, acc[1][2]);
      acc[1][3] = fmaf(hv.y, pv.w, acc[1][3]);
      acc[2][0] = fmaf(hv.z, pv.x, acc[2][0]);
      acc[2][1] = fmaf(hv.z, pv.y, acc[2][1]);
      acc[2][2] = fmaf(hv.z, pv.z, acc[2][2]);
      acc[2][3] = fmaf(hv.z, pv.w, acc[2][3]);
      acc[3][0] = fmaf(hv.w, pv.x, acc[3][0]);
      acc[3][1] = fmaf(hv.w, pv.y, acc[3][1]);
      acc[3][2] = fmaf(hv.w, pv.z, acc[3][2]);
      acc[3][3] = fmaf(hv.w, pv.w, acc[3][3]);
    }
    __syncthreads();
  }

  float4 b1v = *(const float4*)(pb1 + (tx << 2));
  float4 p2v = *(const float4*)(P2 + (tx << 2));
  float pb2v = pb2[0];
#pragma unroll
  for (int g = 0; g < 4; ++g) {
    float r = fmaxf(acc[g][0] + b1v.x, 0.f) * p2v.x +
              fmaxf(acc[g][1] + b1v.y, 0.f) * p2v.y +
              fmaxf(acc[g][2] + b1v.z, 0.f) * p2v.z +
              fmaxf(acc[g][3] + b1v.w, 0.f) * p2v.w;
#pragma unroll
    for (int o = 32; o > 0; o >>= 1) r += __shfl_xor(r, o, 64);
    if (tx == 0) pred[g0 + (tg << 2) + g] = r + pb2v;
  }
}

// ---------------- host orchestration ----------------

extern "C" void kernel_launch(void* const* d_in, const int* in_sizes, int n_in,
                              void* d_out, int out_size, void* d_ws, size_t ws_size,
                              hipStream_t stream) {
  const float* feats = (const float*)d_in[0];
  const int* src = (const int*)d_in[1];
  const int* dst = (const int*)d_in[2];
  const int* gids = (const int*)d_in[3];
  const float* W1 = (const float*)d_in[4];
  const float* b1 = (const float*)d_in[5];
  const float* W2 = (const float*)d_in[6];
  const float* b2 = (const float*)d_in[7];
  const float* W3 = (const float*)d_in[8];
  const float* b3 = (const float*)d_in[9];
  const float* w_atom = (const float*)d_in[10];
  const float* b_atom = (const float*)d_in[11];
  const float* P1 = (const float*)d_in[12];
  const float* pb1 = (const float*)d_in[13];
  const float* P2 = (const float*)d_in[14];
  const float* pb2 = (const float*)d_in[15];
  float* out = (float*)d_out;

  char* base = (char*)d_ws;
  size_t off = 0;
  auto alloc = [&](size_t bytes) -> void* {
    void* p = base + off;
    off = (off + bytes + 511) & ~(size_t)511;
    return p;
  };
  int* outd = (int*)alloc((size_t)N_NODESC * 4);
  int* ind = (int*)alloc((size_t)N_NODESC * 4);
  float* onorm = (float*)alloc((size_t)N_NODESC * 4);
  float* inorm = (float*)alloc((size_t)N_NODESC * 4);
  int* offs = (int*)alloc((size_t)(N_NODESC + 1) * 4);
  int* cursor = (int*)alloc((size_t)N_NODESC * 4);
  int* csr = (int*)alloc((size_t)N_EDGESC * 4);
  float* agg1 = (float*)alloc((size_t)N_NODESC * IN_F * 4);
  float* bufA = (float*)alloc((size_t)N_NODESC * HID * 4);
  float* bufB = (float*)alloc((size_t)N_NODESC * HID * 4);
  unsigned* mkeys = (unsigned*)alloc((size_t)N_GRAPHSC * HID * 4);

  hipMemsetAsync(outd, 0, (size_t)N_NODESC * 4, stream);
  hipMemsetAsync(ind, 0, (size_t)N_NODESC * 4, stream);
  hipMemsetAsync(cursor, 0, (size_t)N_NODESC * 4, stream);
  hipMemsetAsync(mkeys, 0, (size_t)N_GRAPHSC * HID * 4, stream);
  hipMemsetAsync(out, 0, (size_t)out_size * 4, stream);

  k_degrees<<<(N_EDGESC + 255) / 256, 256, 0, stream>>>(src, dst, outd, ind);
  k_norms<<<(N_NODESC + 255) / 256, 256, 0, stream>>>(outd, ind, onorm, inorm);
  k_scan<<<1, 1024, 0, stream>>>(ind, offs);
  k_fill<<<(N_EDGESC + 255) / 256, 256, 0, stream>>>(src, dst, offs, cursor, csr);

  // layer 1
  k_agg16<<<(N_NODESC * IN_F + 255) / 256, 256, 0, stream>>>(feats, offs, csr, onorm,
                                                             inorm, agg1);
  k_mm16<<<2048, 256, 0, stream>>>(agg1, W1, b1, bufA);

  // layer 2
  k_agg256<<<(N_NODESC * 64 + 255) / 256, 256, 0, stream>>>(bufA, offs, csr, onorm,
                                                            inorm, bufB);
  k_gemm<<<dim3((N_NODESC + GBM - 1) / GBM, 2), 256, 0, stream>>>(bufB, W2, b2, bufA,
                                                                  N_NODESC);
  // layer 3
  k_agg256<<<(N_NODESC * 64 + 255) / 256, 256, 0, stream>>>(bufA, offs, csr, onorm,
                                                            inorm, bufB);
  k_gemm<<<dim3((N_NODESC + GBM - 1) / GBM, 2), 256, 0, stream>>>(bufB, W3, b3, bufA,
                                                                  N_NODESC);

  // readout + predictor
  int rwaves = (N_NODESC + RCHUNK - 1) / RCHUNK;
  k_readout<<<(rwaves * 64 + 255) / 256, 256, 0, stream>>>(bufA, gids, w_atom, b_atom,
                                                           out, mkeys);
  k_finalize<<<(N_GRAPHSC * HID + 255) / 256, 256, 0, stream>>>(mkeys, out);
  k_pred<<<N_GRAPHSC / 16, 256, 0, stream>>>(out, P1, pb1, P2, pb2,
                                             out + (size_t)N_GRAPHSC * 512);
}